// Round 1
// baseline (599.028 us; speedup 1.0000x reference)
//
#include <hip/hip_runtime.h>

constexpr int IN_DIM  = 256;
constexpr int OUT_DIM = 64;

// -------- GEMM: xw[N,64] = x[N,256] @ W[256,64] (fp32 vector ALU) --------
// Block = 256 threads (4 waves). Each block computes a 32-row tile.
// Wave w handles rows w*8 .. w*8+7; lane j owns output column j.
// W lives in LDS; per K-chunk (64) each thread copies its column slice into
// registers (stride-64 LDS reads -> 2-way bank alias, free). x rows staged in
// LDS, consumed as broadcast float4 reads (1 LDS instr per 4 FMAs).
__global__ __launch_bounds__(256) void gemm_xw(const float* __restrict__ x,
                                               const float* __restrict__ W,
                                               float* __restrict__ xw, int N) {
    __shared__ float sW[IN_DIM * OUT_DIM];   // 64 KiB
    __shared__ float sX[32 * IN_DIM];        // 32 KiB
    const int tid  = threadIdx.x;
    const int lane = tid & 63;
    const int wave = tid >> 6;
    const int row0 = blockIdx.x * 32;

    // stage whole W: 16384 floats = 4096 float4, 16 per thread, coalesced
#pragma unroll
    for (int i = 0; i < 16; ++i) {
        int idx = tid + i * 256;
        reinterpret_cast<float4*>(sW)[idx] =
            reinterpret_cast<const float4*>(W)[idx];
    }
    // stage 32 x-rows: 2048 float4, 8 per thread, coalesced
#pragma unroll
    for (int i = 0; i < 8; ++i) {
        int idx = tid + i * 256;
        int r   = idx >> 6;   // 64 float4 per row
        int c4  = idx & 63;
        float4 v = make_float4(0.f, 0.f, 0.f, 0.f);
        if (row0 + r < N)
            v = reinterpret_cast<const float4*>(x + (size_t)(row0 + r) * IN_DIM)[c4];
        reinterpret_cast<float4*>(sX)[idx] = v;
    }
    __syncthreads();

    float acc[8];
#pragma unroll
    for (int r = 0; r < 8; ++r) acc[r] = 0.f;

    float wreg[64];
#pragma unroll 1
    for (int c = 0; c < 4; ++c) {
#pragma unroll
        for (int kk = 0; kk < 64; ++kk)
            wreg[kk] = sW[(c * 64 + kk) * OUT_DIM + lane];
#pragma unroll
        for (int r = 0; r < 8; ++r) {
            const float4* xr = reinterpret_cast<const float4*>(
                sX + (wave * 8 + r) * IN_DIM + c * 64);
#pragma unroll
            for (int q = 0; q < 16; ++q) {
                float4 xv = xr[q];                 // broadcast (all lanes same addr)
                acc[r] += xv.x * wreg[4 * q + 0];
                acc[r] += xv.y * wreg[4 * q + 1];
                acc[r] += xv.z * wreg[4 * q + 2];
                acc[r] += xv.w * wreg[4 * q + 3];
            }
        }
    }

#pragma unroll
    for (int r = 0; r < 8; ++r) {
        int row = row0 + wave * 8 + r;
        if (row < N)
            xw[(size_t)row * OUT_DIM + lane] = acc[r];   // coalesced 256B/row
    }
}

// -------- scatter: out[dst] += w * xw[src], atomics, 1 wave per edge --------
__global__ __launch_bounds__(256) void scatter_edges(
        const float* __restrict__ xw, const int* __restrict__ esrc,
        const int* __restrict__ edst, const float* __restrict__ ew,
        float* __restrict__ out, int E) {
    int e = blockIdx.x * 4 + (threadIdx.x >> 6);
    if (e >= E) return;
    int lane = threadIdx.x & 63;
    int s = esrc[e];
    int d = edst[e];
    float w = ew[e];
    float v = xw[(size_t)s * OUT_DIM + lane] * w;   // gather, L3-resident
    atomicAdd(out + (size_t)d * OUT_DIM + lane, v);
}

// -------- relu in place --------
__global__ __launch_bounds__(256) void relu_k(float* __restrict__ out, int n4) {
    int i = blockIdx.x * blockDim.x + threadIdx.x;
    int stride = gridDim.x * blockDim.x;
    for (; i < n4; i += stride) {
        float4 v = reinterpret_cast<float4*>(out)[i];
        v.x = fmaxf(v.x, 0.f);
        v.y = fmaxf(v.y, 0.f);
        v.z = fmaxf(v.z, 0.f);
        v.w = fmaxf(v.w, 0.f);
        reinterpret_cast<float4*>(out)[i] = v;
    }
}

extern "C" void kernel_launch(void* const* d_in, const int* in_sizes, int n_in,
                              void* d_out, int out_size, void* d_ws, size_t ws_size,
                              hipStream_t stream) {
    const float* x    = (const float*)d_in[0];
    const float* W    = (const float*)d_in[1];
    const int*   esrc = (const int*)d_in[2];
    const int*   edst = (const int*)d_in[3];
    const float* ew   = (const float*)d_in[4];
    float* out = (float*)d_out;

    const int N = in_sizes[0] / IN_DIM;   // 100000
    const int E = in_sizes[2];            // 1600000

    float* xw = (float*)d_ws;             // N*64*4 = 25.6 MB scratch

    // out accumulates via atomics -> must start from zero every call
    hipMemsetAsync(d_out, 0, (size_t)out_size * sizeof(float), stream);

    gemm_xw<<<(N + 31) / 32, 256, 0, stream>>>(x, W, xw, N);
    scatter_edges<<<(E + 3) / 4, 256, 0, stream>>>(xw, esrc, edst, ew, out, E);
    relu_k<<<2048, 256, 0, stream>>>(out, out_size / 4);
}

// Round 2
// 521.011 us; speedup vs baseline: 1.1497x; 1.1497x over previous
//
#include <hip/hip_runtime.h>

constexpr int IN_DIM  = 256;
constexpr int OUT_DIM = 64;

// ---------------- GEMM: xw[N,64] = x[N,256] @ W[256,64], fp32 VALU ----------
// Block=256 (4 waves). Wave owns 8 rows; lane j owns output column j.
// No LDS: W chunk loaded coalesced from global (L2-resident, 64 KiB total),
// x read as wave-uniform broadcast float4 (scalarizes to s_load).
__global__ __launch_bounds__(256, 4) void gemm_xw(const float* __restrict__ x,
                                                  const float* __restrict__ W,
                                                  float* __restrict__ xw, int N) {
    const int lane = threadIdx.x & 63;
    const int wave = threadIdx.x >> 6;
    const int row0 = blockIdx.x * 32 + wave * 8;

    const float4* xp[8];
#pragma unroll
    for (int r = 0; r < 8; ++r) {
        int row = row0 + r;
        if (row > N - 1) row = N - 1;          // clamp (last block only)
        xp[r] = reinterpret_cast<const float4*>(x + (size_t)row * IN_DIM);
    }

    float acc[8];
#pragma unroll
    for (int r = 0; r < 8; ++r) acc[r] = 0.f;

    float wreg[64];
#pragma unroll 1
    for (int c = 0; c < 4; ++c) {
        // W[k][lane] for k in [c*64, c*64+64): coalesced 256B loads, L1/L2 hit
#pragma unroll
        for (int kk = 0; kk < 64; ++kk)
            wreg[kk] = W[(size_t)(c * 64 + kk) * OUT_DIM + lane];
#pragma unroll
        for (int q = 0; q < 16; ++q) {
#pragma unroll
            for (int r = 0; r < 8; ++r) {
                float4 xv = xp[r][c * 16 + q];  // wave-uniform broadcast
                acc[r] += xv.x * wreg[4 * q + 0];
                acc[r] += xv.y * wreg[4 * q + 1];
                acc[r] += xv.z * wreg[4 * q + 2];
                acc[r] += xv.w * wreg[4 * q + 3];
            }
        }
    }

#pragma unroll
    for (int r = 0; r < 8; ++r) {
        int row = row0 + r;
        if (row < N)
            xw[(size_t)row * OUT_DIM + lane] = acc[r];   // coalesced 256B/row
    }
}

// ---------------- CSR build: histogram -> scan -> bucket fill ---------------
__global__ __launch_bounds__(256) void hist_k(const int* __restrict__ edst,
                                              int* __restrict__ cnt, int E) {
    int e = blockIdx.x * 256 + threadIdx.x;
    if (e < E) atomicAdd(&cnt[edst[e]], 1);
}

// block-level exclusive scan (1024 wide), partial: off[i] = excl within block
__global__ __launch_bounds__(1024) void scan1_k(const int* __restrict__ cnt,
                                                int* __restrict__ off,
                                                int* __restrict__ bsum, int N) {
    __shared__ int s[1024];
    int t = threadIdx.x;
    int gid = blockIdx.x * 1024 + t;
    int v = (gid < N) ? cnt[gid] : 0;
    s[t] = v;
    __syncthreads();
#pragma unroll
    for (int o = 1; o < 1024; o <<= 1) {
        int a = (t >= o) ? s[t - o] : 0;
        __syncthreads();
        s[t] += a;
        __syncthreads();
    }
    if (gid < N) off[gid] = s[t] - v;          // exclusive, block-local
    if (t == 1023) bsum[blockIdx.x] = s[t];    // block total
}

// scan of block sums (<=128 blocks)
__global__ __launch_bounds__(128) void scan2_k(const int* __restrict__ bsum,
                                               int* __restrict__ bscan, int nb) {
    __shared__ int s[128];
    int t = threadIdx.x;
    int v = (t < nb) ? bsum[t] : 0;
    s[t] = v;
    __syncthreads();
#pragma unroll
    for (int o = 1; o < 128; o <<= 1) {
        int a = (t >= o) ? s[t - o] : 0;
        __syncthreads();
        s[t] += a;
        __syncthreads();
    }
    if (t < nb) bscan[t] = s[t] - v;           // exclusive
}

// add block prefix; also copy to cursor; thread 0 writes off[N]=cur[N]=E
__global__ __launch_bounds__(1024) void scan3_k(int* __restrict__ off,
                                                int* __restrict__ cur,
                                                const int* __restrict__ bscan,
                                                int N, int E) {
    int gid = blockIdx.x * 1024 + threadIdx.x;
    if (gid < N) {
        int o = off[gid] + bscan[blockIdx.x];
        off[gid] = o;
        cur[gid] = o;
    }
    if (gid == 0) { off[N] = E; cur[N] = E; }
}

// fill buckets: val[slot] = {src, bits(w)} grouped by dst
__global__ __launch_bounds__(256) void fill_k(const int* __restrict__ esrc,
                                              const int* __restrict__ edst,
                                              const float* __restrict__ ew,
                                              int* __restrict__ cur,
                                              int2* __restrict__ val, int E) {
    int e = blockIdx.x * 256 + threadIdx.x;
    if (e >= E) return;
    int d = edst[e];
    int slot = atomicAdd(&cur[d], 1);
    val[slot] = make_int2(esrc[e], __float_as_int(ew[e]));
}

// ---------------- gather: one wave per dst node, fused ReLU -----------------
__global__ __launch_bounds__(256) void gather_k(const float* __restrict__ xw,
                                                const int2* __restrict__ val,
                                                const int* __restrict__ off,
                                                float* __restrict__ out, int N) {
    int d = blockIdx.x * 4 + (threadIdx.x >> 6);
    if (d >= N) return;
    int lane = threadIdx.x & 63;
    int b = off[d], e = off[d + 1];
    float acc = 0.f;
    int i = b;
    for (; i + 4 <= e; i += 4) {               // 4-deep ILP
        int2 r0 = val[i + 0];
        int2 r1 = val[i + 1];
        int2 r2 = val[i + 2];
        int2 r3 = val[i + 3];
        float v0 = xw[(size_t)r0.x * OUT_DIM + lane];
        float v1 = xw[(size_t)r1.x * OUT_DIM + lane];
        float v2 = xw[(size_t)r2.x * OUT_DIM + lane];
        float v3 = xw[(size_t)r3.x * OUT_DIM + lane];
        acc += __int_as_float(r0.y) * v0;
        acc += __int_as_float(r1.y) * v1;
        acc += __int_as_float(r2.y) * v2;
        acc += __int_as_float(r3.y) * v3;
    }
    for (; i < e; ++i) {
        int2 r = val[i];
        acc += __int_as_float(r.y) * xw[(size_t)r.x * OUT_DIM + lane];
    }
    out[(size_t)d * OUT_DIM + lane] = fmaxf(acc, 0.f);
}

extern "C" void kernel_launch(void* const* d_in, const int* in_sizes, int n_in,
                              void* d_out, int out_size, void* d_ws, size_t ws_size,
                              hipStream_t stream) {
    const float* x    = (const float*)d_in[0];
    const float* W    = (const float*)d_in[1];
    const int*   esrc = (const int*)d_in[2];
    const int*   edst = (const int*)d_in[3];
    const float* ew   = (const float*)d_in[4];
    float* out = (float*)d_out;

    const int N = in_sizes[0] / IN_DIM;   // 100000
    const int E = in_sizes[2];            // 1600000

    // ---- workspace layout (bytes) ----
    char* ws = (char*)d_ws;
    float* xw  = (float*)ws;                                  // N*64*4 = 25.6MB
    size_t o   = (size_t)N * OUT_DIM * sizeof(float);
    int2* val  = (int2*)(ws + o);   o += (size_t)E * 8;       // 12.8MB
    int* cnt   = (int*)(ws + o);    o += (size_t)N * 4;
    int* off   = (int*)(ws + o);    o += (size_t)(N + 1) * 4;
    int* cur   = (int*)(ws + o);    o += (size_t)(N + 1) * 4;
    int* bsum  = (int*)(ws + o);    o += 128 * 4;
    int* bscan = (int*)(ws + o);

    const int nb1 = (N + 1023) / 1024;    // 98 scan blocks

    hipMemsetAsync(cnt, 0, (size_t)N * sizeof(int), stream);

    gemm_xw<<<(N + 31) / 32, 256, 0, stream>>>(x, W, xw, N);
    hist_k <<<(E + 255) / 256, 256, 0, stream>>>(edst, cnt, E);
    scan1_k<<<nb1, 1024, 0, stream>>>(cnt, off, bsum, N);
    scan2_k<<<1, 128, 0, stream>>>(bsum, bscan, nb1);
    scan3_k<<<nb1, 1024, 0, stream>>>(off, cur, bscan, N, E);
    fill_k <<<(E + 255) / 256, 256, 0, stream>>>(esrc, edst, ew, cur, val, E);
    gather_k<<<(N + 3) / 4, 256, 0, stream>>>(xw, val, off, out, N);
}

// Round 3
// 283.907 us; speedup vs baseline: 2.1099x; 1.8351x over previous
//
#include <hip/hip_runtime.h>

constexpr int IN_DIM  = 256;
constexpr int OUT_DIM = 64;

typedef __attribute__((ext_vector_type(8))) short bf16x8;   // 8 bf16 = 4 VGPR
typedef __attribute__((ext_vector_type(4))) float f32x4;    // MFMA accumulator

// ---- W fragment precompute: per (ktile,ntile,lane) a short8 hi and lo ------
// B-operand layout for mfma_f32_16x16x32_bf16: lane l supplies
// B[k][col] with col = l&15, k = kt*32 + 8*(l>>4) + j (j=0..7 packed in order).
__global__ __launch_bounds__(64) void wfrag_k(const float* __restrict__ W,
                                              bf16x8* __restrict__ fragH,
                                              bf16x8* __restrict__ fragL) {
    const int kt = blockIdx.x >> 2;        // 0..7
    const int nt = blockIdx.x & 3;         // 0..3
    const int l  = threadIdx.x;            // 0..63
    const int col = nt * 16 + (l & 15);
    const int k0  = kt * 32 + (l >> 4) * 8;
    bf16x8 h, lo;
#pragma unroll
    for (int j = 0; j < 8; ++j) {
        float f = W[(size_t)(k0 + j) * OUT_DIM + col];
        unsigned u = __float_as_uint(f);
        h[j] = (short)(u >> 16);                               // truncate hi
        float r = f - __uint_as_float(u & 0xFFFF0000u);
        lo[j] = (short)(__float_as_uint(r) >> 16);             // truncate lo
    }
    fragH[blockIdx.x * 64 + l] = h;
    fragL[blockIdx.x * 64 + l] = lo;
}

// ---- GEMM via bf16 MFMA, split-precision (xh*wh + xh*wl + xl*wh) -----------
// Block = 4 waves; wave owns 32 rows (2 16-row MFMA subtiles), all 64 cols.
// No LDS, no syncthreads. x read once, coalesced (wave covers 16 rows x 128B
// contiguous per ktile). xw written as bf16 (RTN) to halve gather traffic.
__global__ __launch_bounds__(256) void gemm_xw(const float* __restrict__ x,
                                               const bf16x8* __restrict__ fragH,
                                               const bf16x8* __restrict__ fragL,
                                               unsigned short* __restrict__ xw,
                                               int N) {
    const int lane = threadIdx.x & 63;
    const int wave = threadIdx.x >> 6;
    const int rowbase = (blockIdx.x * 4 + wave) * 32;
    if (rowbase >= N) return;
    const int rlo = lane & 15;
    const int khi = lane >> 4;

    f32x4 acc[2][4];
#pragma unroll
    for (int t = 0; t < 2; ++t)
#pragma unroll
        for (int nt = 0; nt < 4; ++nt) acc[t][nt] = (f32x4){0.f, 0.f, 0.f, 0.f};

#pragma unroll 1
    for (int kt = 0; kt < 8; ++kt) {
        bf16x8 bh[4], bl[4];
#pragma unroll
        for (int nt = 0; nt < 4; ++nt) {
            bh[nt] = fragH[(kt * 4 + nt) * 64 + lane];   // coalesced 16B, L2-hot
            bl[nt] = fragL[(kt * 4 + nt) * 64 + lane];
        }
#pragma unroll
        for (int t = 0; t < 2; ++t) {
            int row = rowbase + t * 16 + rlo;
            if (row > N - 1) row = N - 1;
            const float4* xp = reinterpret_cast<const float4*>(
                x + (size_t)row * IN_DIM + kt * 32 + khi * 8);
            float4 a0 = xp[0];
            float4 a1 = xp[1];
            float f[8] = {a0.x, a0.y, a0.z, a0.w, a1.x, a1.y, a1.z, a1.w};
            bf16x8 ah, al;
#pragma unroll
            for (int j = 0; j < 8; ++j) {
                unsigned u = __float_as_uint(f[j]);
                ah[j] = (short)(u >> 16);
                float r = f[j] - __uint_as_float(u & 0xFFFF0000u);
                al[j] = (short)(__float_as_uint(r) >> 16);
            }
#pragma unroll
            for (int nt = 0; nt < 4; ++nt) {
                acc[t][nt] = __builtin_amdgcn_mfma_f32_16x16x32_bf16(
                    ah, bh[nt], acc[t][nt], 0, 0, 0);
                acc[t][nt] = __builtin_amdgcn_mfma_f32_16x16x32_bf16(
                    ah, bl[nt], acc[t][nt], 0, 0, 0);
                acc[t][nt] = __builtin_amdgcn_mfma_f32_16x16x32_bf16(
                    al, bh[nt], acc[t][nt], 0, 0, 0);
            }
        }
    }

    // C/D layout: col = lane&15, row = 4*(lane>>4) + reg. Store bf16 (RTN).
#pragma unroll
    for (int t = 0; t < 2; ++t)
#pragma unroll
        for (int nt = 0; nt < 4; ++nt)
#pragma unroll
            for (int i = 0; i < 4; ++i) {
                int row = rowbase + t * 16 + khi * 4 + i;
                int col = nt * 16 + rlo;
                if (row < N) {
                    unsigned u = __float_as_uint(acc[t][nt][i]);
                    u += 0x7fffu + ((u >> 16) & 1u);           // round-to-nearest
                    xw[(size_t)row * OUT_DIM + col] = (unsigned short)(u >> 16);
                }
            }
}

// ---------------- CSR build: histogram -> scan -> bucket fill ---------------
__global__ __launch_bounds__(256) void hist_k(const int* __restrict__ edst,
                                              int* __restrict__ cnt, int E) {
    int base = (blockIdx.x * 256 + threadIdx.x) * 4;
    if (base + 3 < E) {
        int4 d4 = *reinterpret_cast<const int4*>(edst + base);
        atomicAdd(&cnt[d4.x], 1);
        atomicAdd(&cnt[d4.y], 1);
        atomicAdd(&cnt[d4.z], 1);
        atomicAdd(&cnt[d4.w], 1);
    } else {
        for (int e = base; e < E; ++e) atomicAdd(&cnt[edst[e]], 1);
    }
}

__global__ __launch_bounds__(1024) void scan1_k(const int* __restrict__ cnt,
                                                int* __restrict__ off,
                                                int* __restrict__ bsum, int N) {
    __shared__ int s[1024];
    int t = threadIdx.x;
    int gid = blockIdx.x * 1024 + t;
    int v = (gid < N) ? cnt[gid] : 0;
    s[t] = v;
    __syncthreads();
#pragma unroll
    for (int o = 1; o < 1024; o <<= 1) {
        int a = (t >= o) ? s[t - o] : 0;
        __syncthreads();
        s[t] += a;
        __syncthreads();
    }
    if (gid < N) off[gid] = s[t] - v;
    if (t == 1023) bsum[blockIdx.x] = s[t];
}

__global__ __launch_bounds__(128) void scan2_k(const int* __restrict__ bsum,
                                               int* __restrict__ bscan, int nb) {
    __shared__ int s[128];
    int t = threadIdx.x;
    int v = (t < nb) ? bsum[t] : 0;
    s[t] = v;
    __syncthreads();
#pragma unroll
    for (int o = 1; o < 128; o <<= 1) {
        int a = (t >= o) ? s[t - o] : 0;
        __syncthreads();
        s[t] += a;
        __syncthreads();
    }
    if (t < nb) bscan[t] = s[t] - v;
}

__global__ __launch_bounds__(1024) void scan3_k(int* __restrict__ off,
                                                int* __restrict__ cur,
                                                const int* __restrict__ bscan,
                                                int N, int E) {
    int gid = blockIdx.x * 1024 + threadIdx.x;
    if (gid < N) {
        int o = off[gid] + bscan[blockIdx.x];
        off[gid] = o;
        cur[gid] = o;
    }
    if (gid == 0) { off[N] = E; cur[N] = E; }
}

__global__ __launch_bounds__(256) void fill_k(const int* __restrict__ esrc,
                                              const int* __restrict__ edst,
                                              const float* __restrict__ ew,
                                              int* __restrict__ cur,
                                              int2* __restrict__ val, int E) {
    int e = blockIdx.x * 256 + threadIdx.x;
    if (e >= E) return;
    int d = edst[e];
    int slot = atomicAdd(&cur[d], 1);
    val[slot] = make_int2(esrc[e], __float_as_int(ew[e]));
}

// ---------------- gather: one wave per dst node, fused ReLU -----------------
__global__ __launch_bounds__(256) void gather_k(const unsigned short* __restrict__ xw,
                                                const int2* __restrict__ val,
                                                const int* __restrict__ off,
                                                float* __restrict__ out, int N) {
    int d = blockIdx.x * 4 + (threadIdx.x >> 6);
    if (d >= N) return;
    int lane = threadIdx.x & 63;
    int b = off[d], e = off[d + 1];
    float acc = 0.f;
    int i = b;
    for (; i + 4 <= e; i += 4) {
        int2 r0 = val[i + 0];
        int2 r1 = val[i + 1];
        int2 r2 = val[i + 2];
        int2 r3 = val[i + 3];
        float v0 = __uint_as_float((unsigned)xw[(size_t)r0.x * OUT_DIM + lane] << 16);
        float v1 = __uint_as_float((unsigned)xw[(size_t)r1.x * OUT_DIM + lane] << 16);
        float v2 = __uint_as_float((unsigned)xw[(size_t)r2.x * OUT_DIM + lane] << 16);
        float v3 = __uint_as_float((unsigned)xw[(size_t)r3.x * OUT_DIM + lane] << 16);
        acc += __int_as_float(r0.y) * v0;
        acc += __int_as_float(r1.y) * v1;
        acc += __int_as_float(r2.y) * v2;
        acc += __int_as_float(r3.y) * v3;
    }
    for (; i < e; ++i) {
        int2 r = val[i];
        acc += __int_as_float(r.y) *
               __uint_as_float((unsigned)xw[(size_t)r.x * OUT_DIM + lane] << 16);
    }
    out[(size_t)d * OUT_DIM + lane] = fmaxf(acc, 0.f);
}

extern "C" void kernel_launch(void* const* d_in, const int* in_sizes, int n_in,
                              void* d_out, int out_size, void* d_ws, size_t ws_size,
                              hipStream_t stream) {
    const float* x    = (const float*)d_in[0];
    const float* W    = (const float*)d_in[1];
    const int*   esrc = (const int*)d_in[2];
    const int*   edst = (const int*)d_in[3];
    const float* ew   = (const float*)d_in[4];
    float* out = (float*)d_out;

    const int N = in_sizes[0] / IN_DIM;   // 100000
    const int E = in_sizes[2];            // 1600000

    // ---- workspace layout (16B-aligned segments) ----
    char* ws = (char*)d_ws;
    size_t o = 0;
    bf16x8* fragH = (bf16x8*)(ws + o);  o += 32 * 64 * 16;               // 32 KB
    bf16x8* fragL = (bf16x8*)(ws + o);  o += 32 * 64 * 16;               // 32 KB
    unsigned short* xw = (unsigned short*)(ws + o);
    o += (size_t)N * OUT_DIM * 2;                                        // 12.8 MB
    int2* val = (int2*)(ws + o);        o += (size_t)E * 8;              // 12.8 MB
    int* cnt  = (int*)(ws + o);         o += (size_t)N * 4;
    int* off  = (int*)(ws + o);         o += (size_t)(N + 1) * 4;
    int* cur  = (int*)(ws + o);         o += (size_t)(N + 1) * 4;
    int* bsum = (int*)(ws + o);         o += 128 * 4;
    int* bscan = (int*)(ws + o);

    const int nb1 = (N + 1023) / 1024;

    hipMemsetAsync(cnt, 0, (size_t)N * sizeof(int), stream);

    wfrag_k<<<32, 64, 0, stream>>>(W, fragH, fragL);
    gemm_xw<<<(N + 127) / 128, 256, 0, stream>>>(x, fragH, fragL, xw, N);
    hist_k <<<(E / 4 + 255) / 256 + 1, 256, 0, stream>>>(edst, cnt, E);
    scan1_k<<<nb1, 1024, 0, stream>>>(cnt, off, bsum, N);
    scan2_k<<<1, 128, 0, stream>>>(bsum, bscan, nb1);
    scan3_k<<<nb1, 1024, 0, stream>>>(off, cur, bscan, N, E);
    fill_k <<<(E + 255) / 256, 256, 0, stream>>>(esrc, edst, ew, cur, val, E);
    gather_k<<<(N + 3) / 4, 256, 0, stream>>>(xw, val, off, out, N);
}